// Round 2
// baseline (114.816 us; speedup 1.0000x reference)
//
#include <hip/hip_runtime.h>
#include <hip/hip_bf16.h>
#include <math.h>

// GaussianModel histogram splat, restructured:
//  k1: per-point constants -> LDS -> each thread accumulates 2 bins over a
//      256-point chunk -> coalesced partials[block][512] into d_ws.
//  k2: 16-block column reduction of partials, /r^2, 16-way atomicAdd.
//
// Inner loop in polynomial form (r^2 per-thread constant):
//  arg = alpha*r^2 + beta*r + gamma ; e = exp2(arg)
//  w   = b*r + a'                   ; contrib = clamp(e*w, 0, 1)
// Upper clip provably inactive (sigma >= BIN_RES/2 => pdf*BIN_RES/2 <= 0.607)
// so intensity is folded into the per-point constants and saturate is exact.

#define NBINS 512
#define CHUNK 256
#define NTHREADS 256
#define K_SQRT_HALF_PI 0.3989422804014327f   // sqrt(0.5/pi)
#define LOG2E 1.4426950408889634f

__device__ __forceinline__ float fast_exp2(float x) {
#if __has_builtin(__builtin_amdgcn_exp2f)
    return __builtin_amdgcn_exp2f(x);
#else
    return exp2f(x);
#endif
}

__global__ __launch_bounds__(NTHREADS) void gauss_partial(
    const float* __restrict__ means,
    const float* __restrict__ scan_point,
    const float* __restrict__ colours,
    const float* __restrict__ coeffs,
    const float* __restrict__ opac,
    const float* __restrict__ scales,
    const int* __restrict__ view_id,
    float* __restrict__ partials,   // [gridDim.x][NBINS]
    int n)
{
    __shared__ float4 s_q[CHUNK];   // {alpha, beta, gamma, b}
    __shared__ float  s_a[CHUNK];   // a'
    const int t = threadIdx.x;
    const int base = blockIdx.x * CHUNK;

    // stage per-point constants (one point per thread)
    {
        const int p = base + t;
        float4 q = make_float4(0.f, 0.f, 0.f, 0.f);  // inert: exp2(0)*0 -> 0
        float a5 = 0.f;
        if (p < n) {
            const int vid = view_id[0];              // VIEW_NUM == 1
            float dx = means[3 * p + 0] - scan_point[0];
            float dy = means[3 * p + 1] - scan_point[1];
            float dz = means[3 * p + 2] - scan_point[2];
            float r0 = sqrtf(fmaf(dx, dx, fmaf(dy, dy, dz * dz)));
            float sg = fmaxf(expf(scales[p]), 0.005f);   // max(exp(scales), BIN_RES/2)
            float inv_s = 1.0f / sg;
            float coeff = 1.0f / (1.0f + expf(-coeffs[p]));
            float op  = opac[p + vid];
            float col = colours[p];
            float ia  = (op * op) * (col * col) * 0.005f;    // intensity * BIN_RES/2
            float alpha = -0.5f * inv_s * inv_s * LOG2E;
            float bw = ia * (1.0f - coeff) * inv_s * inv_s;  // pdf2 weight
            float aw = ia * coeff * K_SQRT_HALF_PI * inv_s;  // pdf1 weight
            q.x = alpha;
            q.y = -2.0f * alpha * r0;          // beta
            q.z = alpha * r0 * r0;             // gamma
            q.w = bw;
            a5  = fmaf(-bw, r0, aw);           // a' = a - b*r0
        }
        s_q[t] = q;
        s_a[t] = a5;
    }
    __syncthreads();

    // 2 bins per thread: t and t+256 (LDS reads amortized over both)
    const float ra = 0.005f * (float)(t + 1);
    const float rb = 0.005f * (float)(t + 1 + 256);
    const float ra2 = ra * ra, rb2 = rb * rb;
    float acca = 0.f, accb = 0.f;
#pragma unroll 4
    for (int k = 0; k < CHUNK; ++k) {
        float4 q = s_q[k];                 // broadcast ds_read_b128
        float a5 = s_a[k];                 // broadcast ds_read_b32
        float arga = fmaf(q.y, ra, fmaf(q.x, ra2, q.z));
        float argb = fmaf(q.y, rb, fmaf(q.x, rb2, q.z));
        float ea = fast_exp2(arga);
        float eb = fast_exp2(argb);
        float wa = fmaf(q.w, ra, a5);
        float wb = fmaf(q.w, rb, a5);
        acca += __saturatef(ea * wa);
        accb += __saturatef(eb * wb);
    }
    float* row = partials + (size_t)blockIdx.x * NBINS;
    row[t]       = acca;                   // coalesced
    row[t + 256] = accb;
}

__global__ __launch_bounds__(NBINS) void gauss_reduce(
    const float* __restrict__ partials, float* __restrict__ out, int nrows)
{
    const int bin = threadIdx.x;
    float acc = 0.f;
    for (int i = blockIdx.x; i < nrows; i += gridDim.x)
        acc += partials[(size_t)i * NBINS + bin];   // wave reads 64 consecutive floats
    const float r = 0.005f * (float)(bin + 1);
    atomicAdd(&out[bin], acc / (r * r));            // 16 contenders per address
}

extern "C" void kernel_launch(void* const* d_in, const int* in_sizes, int n_in,
                              void* d_out, int out_size, void* d_ws, size_t ws_size,
                              hipStream_t stream) {
    const float* means = (const float*)d_in[0];
    const float* scan  = (const float*)d_in[1];
    const float* col   = (const float*)d_in[2];
    const float* cf    = (const float*)d_in[3];
    const float* op    = (const float*)d_in[4];
    const float* sc    = (const float*)d_in[5];
    const int*   vid   = (const int*)d_in[6];
    float* out = (float*)d_out;
    float* partials = (float*)d_ws;

    const int n = in_sizes[2];                     // colours: NUM_POINTS
    const int blocks = (n + CHUNK - 1) / CHUNK;    // 782

    hipMemsetAsync(d_out, 0, (size_t)out_size * sizeof(float), stream);
    gauss_partial<<<blocks, NTHREADS, 0, stream>>>(means, scan, col, cf, op, sc, vid, partials, n);
    gauss_reduce<<<16, NBINS, 0, stream>>>(partials, out, blocks);
}

// Round 3
// 90.921 us; speedup vs baseline: 1.2628x; 1.2628x over previous
//
#include <hip/hip_runtime.h>
#include <hip/hip_bf16.h>
#include <math.h>

// Point-major scatter formulation.
// Per point: contrib(b) = sat( e * (aw + bw*diff) ), diff = r_b - r0,
//   e = exp2(-nalpha*diff^2).
// Sparsity:
//  - bw > 0 always (coeff = sigmoid(0.1*N) in (0.38,0.62)), so for
//    r <= r0 - aw/bw the weight is <= 0 and saturate clips to EXACTLY 0
//    -> exact lower window bound.
//  - above r0 + 8*sigma, e <= e^-32 ~ 1.3e-14 -> skipped mass << 1e-12 abs.
// Window ~ 8.65*sigma ~ 86 bins instead of 512; ~40% of points have no
// in-range bins at all. Scatter into LDS hist (ds_add_f32), one conditional
// global atomic per (block,bin) at the end.
// Upper clip at 1.0 provably inactive (pdf*BIN_RES/2 <= 0.48), so intensity
// folds into aw/bw and __saturatef is exact.

#define NBINS 512
#define TPB 512
#define K_SQRT_HALF_PI 0.3989422804014327f   // sqrt(0.5/pi)
#define LOG2E 1.4426950408889634f

__device__ __forceinline__ float fast_exp2(float x) {
#if __has_builtin(__builtin_amdgcn_exp2f)
    return __builtin_amdgcn_exp2f(x);
#else
    return exp2f(x);
#endif
}

__global__ __launch_bounds__(TPB) void gauss_scatter(
    const float* __restrict__ means,
    const float* __restrict__ scan_point,
    const float* __restrict__ colours,
    const float* __restrict__ coeffs,
    const float* __restrict__ opac,
    const float* __restrict__ scales,
    const int* __restrict__ view_id,
    float* __restrict__ out,
    int n)
{
    __shared__ float hist[NBINS];
    const int t = threadIdx.x;
    hist[t] = 0.f;
    __syncthreads();

    const int p = blockIdx.x * TPB + t;
    if (p < n) {
        const int vid = view_id[0];                  // VIEW_NUM == 1
        float dx = means[3 * p + 0] - scan_point[0];
        float dy = means[3 * p + 1] - scan_point[1];
        float dz = means[3 * p + 2] - scan_point[2];
        float r0 = sqrtf(fmaf(dx, dx, fmaf(dy, dy, dz * dz)));
        float sg = fmaxf(expf(scales[p]), 0.005f);   // max(exp(scales), BIN_RES/2)
        float inv_s = 1.0f / sg;
        float coeff = 1.0f / (1.0f + expf(-coeffs[p]));
        float op  = opac[p + vid];
        float col = colours[p];
        float ia  = (op * op) * (col * col) * 0.005f;    // intensity * BIN_RES/2
        float nalpha = 0.5f * LOG2E * inv_s * inv_s;     // positive; exp2 arg scale
        float aw = ia * coeff * K_SQRT_HALF_PI * inv_s;  // pdf1 weight
        float bw = ia * (1.0f - coeff) * inv_s * inv_s;  // pdf2 weight (>0)

        float rlo = r0 - aw / bw;                    // w <= 0 below this (exact cutoff)
        float rhi = fmaf(8.0f, sg, r0);              // e <= e^-32 above this
        int lo = (int)floorf(rlo * 200.f) - 1;       // bin b: r = 0.005*(b+1); 1 bin slack
        int hi = (int)floorf(rhi * 200.f);           // 1 bin slack
        lo = lo < 0 ? 0 : lo;
        hi = hi > NBINS - 1 ? NBINS - 1 : hi;
        for (int b = lo; b <= hi; ++b) {             // empty when window out of range
            float r = 0.005f * (float)(b + 1);
            float diff = r - r0;
            float e = fast_exp2(-(nalpha * diff) * diff);
            float w = fmaf(bw, diff, aw);
            atomicAdd(&hist[b], __saturatef(e * w)); // ds_add_f32, scattered
        }
    }
    __syncthreads();

    // merge: one conditional global atomic per (block, bin)
    float h = hist[t];
    if (h != 0.f) {
        float r = 0.005f * (float)(t + 1);
        atomicAdd(&out[t], h / (r * r));             // fold /r^DECAY (DECAY=2)
    }
}

extern "C" void kernel_launch(void* const* d_in, const int* in_sizes, int n_in,
                              void* d_out, int out_size, void* d_ws, size_t ws_size,
                              hipStream_t stream) {
    const float* means = (const float*)d_in[0];
    const float* scan  = (const float*)d_in[1];
    const float* col   = (const float*)d_in[2];
    const float* cf    = (const float*)d_in[3];
    const float* op    = (const float*)d_in[4];
    const float* sc    = (const float*)d_in[5];
    const int*   vid   = (const int*)d_in[6];
    float* out = (float*)d_out;

    const int n = in_sizes[2];                       // colours: NUM_POINTS
    hipMemsetAsync(d_out, 0, (size_t)out_size * sizeof(float), stream);
    const int blocks = (n + TPB - 1) / TPB;          // 391
    gauss_scatter<<<blocks, TPB, 0, stream>>>(means, scan, col, cf, op, sc, vid, out, n);
}

// Round 4
// 88.527 us; speedup vs baseline: 1.2970x; 1.0270x over previous
//
#include <hip/hip_runtime.h>
#include <hip/hip_bf16.h>
#include <math.h>

// Point-major scatter with INCREMENTAL exponential over uniform bins.
// contrib(b) = sat(e_b * w_b), e_b = exp2(-nalpha*(r_b-r0)^2), w_b = aw + bw*(r_b-r0).
// Uniform bin pitch D=0.005 => e_{b+1} = e_b * d_b, d_{b+1} = d_b * c,
//   d_lo = exp2(-nalpha*(2*D*diff0 + D^2)), c = exp2(-2*nalpha*D^2),
// so the inner loop has NO transcendentals (3 muls + 1 add + sat-mul + ds_add).
// Windows (unchanged from R3, absmax was 0.0):
//  - bw > 0 always => w <= 0 for r <= r0 - aw/bw: saturate clips to EXACT 0.
//  - above r0 + 8*sigma: e <= 2^-46, skipped mass << 1e-12 absolute.
// Drift of the recurrence: ~n^2/2*eps ~ 1e-3 relative on a contribution
// => ~3e-8 absolute on out (threshold 6.1e-7). 256 blocks (1/CU), grid-stride.

#define NBINS 512
#define TPB 512
#define NBLK 256
#define K_SQRT_HALF_PI 0.3989422804014327f   // sqrt(0.5/pi)
#define LOG2E 1.4426950408889634f

__device__ __forceinline__ float fast_exp2(float x) {
#if __has_builtin(__builtin_amdgcn_exp2f)
    return __builtin_amdgcn_exp2f(x);
#else
    return exp2f(x);
#endif
}

__global__ __launch_bounds__(TPB) void gauss_scatter(
    const float* __restrict__ means,
    const float* __restrict__ scan_point,
    const float* __restrict__ colours,
    const float* __restrict__ coeffs,
    const float* __restrict__ opac,
    const float* __restrict__ scales,
    const int* __restrict__ view_id,
    float* __restrict__ out,
    int n)
{
    __shared__ float hist[NBINS];
    const int t = threadIdx.x;
    hist[t] = 0.f;                               // TPB == NBINS
    __syncthreads();

    const int vid = view_id[0];                  // VIEW_NUM == 1
    const float sx = scan_point[0], sy = scan_point[1], sz = scan_point[2];

    for (int p = blockIdx.x * TPB + t; p < n; p += NBLK * TPB) {
        float dx = means[3 * p + 0] - sx;
        float dy = means[3 * p + 1] - sy;
        float dz = means[3 * p + 2] - sz;
        float r0 = sqrtf(fmaf(dx, dx, fmaf(dy, dy, dz * dz)));
        float sg = fmaxf(expf(scales[p]), 0.005f);   // max(exp(scales), BIN_RES/2)
        float inv_s = 1.0f / sg;
        float coeff = 1.0f / (1.0f + expf(-coeffs[p]));
        float op  = opac[p + vid];
        float col = colours[p];
        float ia  = (op * op) * (col * col) * 0.005f;    // intensity * BIN_RES/2
        float nalpha = 0.5f * LOG2E * inv_s * inv_s;     // exp2-units, positive
        float aw = ia * coeff * K_SQRT_HALF_PI * inv_s;  // pdf1 weight
        float bw = ia * (1.0f - coeff) * inv_s * inv_s;  // pdf2 weight (>0)

        float rlo = r0 - aw / bw;                    // exact w<=0 cutoff
        float rhi = fmaf(8.0f, sg, r0);              // e <= 2^-46 above
        int lo = (int)floorf(rlo * 200.f) - 1;       // bin b: r = 0.005*(b+1); slack bin
        int hi = (int)floorf(rhi * 200.f);
        lo = lo < 0 ? 0 : lo;
        hi = hi > NBINS - 1 ? NBINS - 1 : hi;
        if (lo > hi) continue;

        float diff0 = fmaf(0.005f, (float)(lo + 1), -r0);
        float e = fast_exp2(-(nalpha * diff0) * diff0);
        float d = fast_exp2(-nalpha * fmaf(0.01f, diff0, 2.5e-5f)); // -na*(2D*diff0+D^2)
        const float c = fast_exp2(-nalpha * 5.0e-5f);               // -2*na*D^2
        float w = fmaf(bw, diff0, aw);
        const float bwd = bw * 0.005f;
        for (int b = lo; b <= hi; ++b) {
            atomicAdd(&hist[b], __saturatef(e * w));  // ds_add_f32 no-return
            e *= d;
            d *= c;
            w += bwd;
        }
    }
    __syncthreads();

    // merge: one conditional global atomic per (block, bin); fold /r^2 (DECAY=2)
    float h = hist[t];
    if (h != 0.f) {
        float r = 0.005f * (float)(t + 1);
        atomicAdd(&out[t], h / (r * r));
    }
}

extern "C" void kernel_launch(void* const* d_in, const int* in_sizes, int n_in,
                              void* d_out, int out_size, void* d_ws, size_t ws_size,
                              hipStream_t stream) {
    const float* means = (const float*)d_in[0];
    const float* scan  = (const float*)d_in[1];
    const float* col   = (const float*)d_in[2];
    const float* cf    = (const float*)d_in[3];
    const float* op    = (const float*)d_in[4];
    const float* sc    = (const float*)d_in[5];
    const int*   vid   = (const int*)d_in[6];
    float* out = (float*)d_out;

    const int n = in_sizes[2];                       // colours: NUM_POINTS
    hipMemsetAsync(d_out, 0, (size_t)out_size * sizeof(float), stream);
    gauss_scatter<<<NBLK, TPB, 0, stream>>>(means, scan, col, cf, op, sc, vid, out, n);
}